// Round 1
// baseline (6593.378 us; speedup 1.0000x reference)
//
#include <hip/hip_runtime.h>
#include <math.h>

#define BATCH 4096
#define FEAT 128
#define C_TOTAL 16384
#define OUT_TYPES 512

// ---------------- kernel 1: row sum-of-squares (+ optional scale=exp(2*ls)) ---
// 4 threads per row, float4 loads, 4-lane shuffle reduce.
__global__ void norms_kernel(const float* __restrict__ src, int nrows,
                             float* __restrict__ norm_out,
                             const float* __restrict__ ls,
                             float* __restrict__ scale_out) {
    int t = threadIdx.x;
    int row = blockIdx.x * 64 + (t >> 2);
    int l4 = t & 3;
    if (row >= nrows) return;
    const float4* p = reinterpret_cast<const float4*>(src + (size_t)row * FEAT + l4 * 32);
    float s = 0.f;
#pragma unroll
    for (int i = 0; i < 8; ++i) {
        float4 v = p[i];
        s += v.x * v.x + v.y * v.y + v.z * v.z + v.w * v.w;
    }
    s += __shfl_xor(s, 1);
    s += __shfl_xor(s, 2);
    if (l4 == 0) {
        norm_out[row] = s;
        if (scale_out) scale_out[row] = __expf(2.f * ls[row]);
    }
}

// ---------------- kernel 2: fused pairwise-dist -> phi -> segment-sum ---------
// Block: 16 rows of x, sweeps CCHUNK centres in BN=64 chunks.
// LDS: xs 8KB + cs 32KB + rbf 32KB = 72KB -> 2 blocks/CU.
// Granule-XOR swizzle so compute reads are ds_read_b128 at the BW floor.
#define BM 16
#define BN 64
#define CSPLIT 2
#define CCHUNK (C_TOTAL / CSPLIT) /* 8192 */
#define NCHUNK (CCHUNK / BN)      /* 128 */

__global__ __launch_bounds__(256, 2)
void rbf_kernel(const float* __restrict__ x, const float* __restrict__ centres,
                const float* __restrict__ cc, const float* __restrict__ scale,
                const int* __restrict__ node_id, const float* __restrict__ xx,
                float* __restrict__ parts) {
    __shared__ float xs[BM][FEAT];        // [row][swizzled k]
    __shared__ float cs[BN][FEAT];
    __shared__ float rbf[BM][OUT_TYPES];  // segment accumulator

    const int t = threadIdx.x;
    const int row0 = blockIdx.x * BM;
    const int split = blockIdx.y;
    const int c_base = split * CCHUNK;

    // zero rbf accumulator (LDS is uninitialized)
#pragma unroll
    for (int i = 0; i < (BM * OUT_TYPES) / 256; ++i)
        (&rbf[0][0])[t + i * 256] = 0.f;

    // stage x tile: 16 rows x 32 granules(4 floats); swizzled write, coalesced read
#pragma unroll
    for (int j = 0; j < 2; ++j) {
        int gi = t + j * 256;
        int r = gi >> 5;
        int g = gi & 31;
        float4 v = *reinterpret_cast<const float4*>(x + (size_t)(row0 + r) * FEAT + g * 4);
        *reinterpret_cast<float4*>(&xs[r][4 * (g ^ (r & 7))]) = v;
    }

    const int r0 = t >> 5;   // 0..7  (rows r0, r0+8)
    const int n0 = t & 31;   // 0..31 (cols n0, n0+32)
    const int swr = r0 & 7;
    const int swn = n0 & 7;  // (n0+32)&7 == n0&7, (r0+8)&7 == r0&7
    const float xxr0 = xx[row0 + r0];
    const float xxr1 = xx[row0 + r0 + 8];
    const float* xsr0 = &xs[r0][0];
    const float* xsr1 = &xs[r0 + 8][0];
    const float* csn0 = &cs[n0][0];
    const float* csn1 = &cs[n0 + 32][0];

    for (int ch = 0; ch < NCHUNK; ++ch) {
        const int c0 = c_base + ch * BN;
        __syncthreads();  // protect cs from previous iteration's readers
        // stage 64 centres x 128 feat, coalesced global, swizzled LDS write
#pragma unroll
        for (int j = 0; j < 8; ++j) {
            int gi = t + j * 256;
            int n = gi >> 5;
            int g = gi & 31;
            float4 v = *reinterpret_cast<const float4*>(centres + (size_t)(c0 + n) * FEAT + g * 4);
            *reinterpret_cast<float4*>(&cs[n][4 * (g ^ (n & 7))]) = v;
        }
        __syncthreads();

        float d00 = 0.f, d01 = 0.f, d10 = 0.f, d11 = 0.f;
#pragma unroll
        for (int g = 0; g < 32; ++g) {
            float4 a0 = *reinterpret_cast<const float4*>(xsr0 + 4 * (g ^ swr));
            float4 a1 = *reinterpret_cast<const float4*>(xsr1 + 4 * (g ^ swr));
            float4 b0 = *reinterpret_cast<const float4*>(csn0 + 4 * (g ^ swn));
            float4 b1 = *reinterpret_cast<const float4*>(csn1 + 4 * (g ^ swn));
            d00 += a0.x * b0.x + a0.y * b0.y + a0.z * b0.z + a0.w * b0.w;
            d01 += a0.x * b1.x + a0.y * b1.y + a0.z * b1.z + a0.w * b1.w;
            d10 += a1.x * b0.x + a1.y * b0.y + a1.z * b0.z + a1.w * b0.w;
            d11 += a1.x * b1.x + a1.y * b1.y + a1.z * b1.z + a1.w * b1.w;
        }

        // phi + guarded LDS segment accumulate (exp underflow => skip atomic)
        {
            int ca = c0 + n0, cb = c0 + n0 + 32;
            float sa = scale[ca], sb = scale[cb];
            float na = cc[ca], nb = cc[cb];
            int ta = node_id[ca], tb = node_id[cb];

            float sq, tt;
            sq = fmaxf(xxr0 + na - 2.f * d00, 0.f); tt = sq * sa;
            if (tt < 104.f) atomicAdd(&rbf[r0][ta], __expf(-tt));
            sq = fmaxf(xxr0 + nb - 2.f * d01, 0.f); tt = sq * sb;
            if (tt < 104.f) atomicAdd(&rbf[r0][tb], __expf(-tt));
            sq = fmaxf(xxr1 + na - 2.f * d10, 0.f); tt = sq * sa;
            if (tt < 104.f) atomicAdd(&rbf[r0 + 8][ta], __expf(-tt));
            sq = fmaxf(xxr1 + nb - 2.f * d11, 0.f); tt = sq * sb;
            if (tt < 104.f) atomicAdd(&rbf[r0 + 8][tb], __expf(-tt));
        }
    }
    __syncthreads();

    // write this block's partial [16][512] (no global atomics -> deterministic)
    float* dst = parts + ((size_t)split * BATCH + row0) * OUT_TYPES;
#pragma unroll
    for (int i = 0; i < (BM * OUT_TYPES) / 256; ++i) {
        int idx = t + i * 256;
        dst[idx] = (&rbf[0][0])[idx];
    }
}

// ---------------- kernel 3: out = (p0+p1) @ W^T + b ---------------------------
// 64x64 tile, K-chunks of 32, 4x4 micro-tile, swizzled b128 LDS reads.
#define KC 32
__global__ __launch_bounds__(256)
void lin_kernel(const float* __restrict__ parts, const float* __restrict__ W,
                const float* __restrict__ bias, float* __restrict__ out) {
    __shared__ float as[64][KC];
    __shared__ float bs[64][KC];
    const int t = threadIdx.x;
    const int m0 = blockIdx.y * 64;
    const int n0 = blockIdx.x * 64;
    const float* p0 = parts;
    const float* p1 = parts + (size_t)BATCH * OUT_TYPES;

    const int rr = t >> 4;  // 0..15
    const int nn = t & 15;  // 0..15
    float acc[4][4] = {};

    for (int kc = 0; kc < OUT_TYPES; kc += KC) {
        __syncthreads();
#pragma unroll
        for (int j = 0; j < 2; ++j) {
            int gi = t + j * 256;     // 512 granules per array
            int r = gi >> 3;          // 8 granules per row
            int g = gi & 7;
            size_t off = (size_t)(m0 + r) * OUT_TYPES + kc + g * 4;
            float4 va = *reinterpret_cast<const float4*>(p0 + off);
            float4 vb = *reinterpret_cast<const float4*>(p1 + off);
            va.x += vb.x; va.y += vb.y; va.z += vb.z; va.w += vb.w;
            *reinterpret_cast<float4*>(&as[r][4 * (g ^ (r & 7))]) = va;
            float4 w = *reinterpret_cast<const float4*>(W + (size_t)(n0 + r) * OUT_TYPES + kc + g * 4);
            *reinterpret_cast<float4*>(&bs[r][4 * (g ^ (r & 7))]) = w;
        }
        __syncthreads();
#pragma unroll
        for (int g = 0; g < 8; ++g) {
            float4 a[4], b[4];
#pragma unroll
            for (int i = 0; i < 4; ++i) {
                int r = rr + 16 * i;
                a[i] = *reinterpret_cast<const float4*>(&as[r][4 * (g ^ (r & 7))]);
                int n = nn + 16 * i;
                b[i] = *reinterpret_cast<const float4*>(&bs[n][4 * (g ^ (n & 7))]);
            }
#pragma unroll
            for (int i = 0; i < 4; ++i)
#pragma unroll
                for (int j = 0; j < 4; ++j)
                    acc[i][j] += a[i].x * b[j].x + a[i].y * b[j].y +
                                 a[i].z * b[j].z + a[i].w * b[j].w;
        }
    }

#pragma unroll
    for (int i = 0; i < 4; ++i) {
        int m = m0 + rr + 16 * i;
#pragma unroll
        for (int j = 0; j < 4; ++j) {
            int n = n0 + nn + 16 * j;
            out[(size_t)m * OUT_TYPES + n] = acc[i][j] + bias[n];
        }
    }
}

// ---------------- launch ------------------------------------------------------
extern "C" void kernel_launch(void* const* d_in, const int* in_sizes, int n_in,
                              void* d_out, int out_size, void* d_ws, size_t ws_size,
                              hipStream_t stream) {
    const float* x       = (const float*)d_in[0];
    const float* centres = (const float*)d_in[1];
    const float* ls      = (const float*)d_in[2];
    const int*   node_id = (const int*)d_in[3];
    const float* W       = (const float*)d_in[4];
    const float* bias    = (const float*)d_in[5];
    float* out = (float*)d_out;

    float* ws    = (float*)d_ws;
    float* parts = ws;                                   // 2*4096*512 f32 = 16MB
    float* cc    = parts + 2 * (size_t)BATCH * OUT_TYPES;
    float* scale = cc + C_TOTAL;
    float* xx    = scale + C_TOTAL;

    hipLaunchKernelGGL(norms_kernel, dim3(C_TOTAL / 64), dim3(256), 0, stream,
                       centres, C_TOTAL, cc, ls, scale);
    hipLaunchKernelGGL(norms_kernel, dim3(BATCH / 64), dim3(256), 0, stream,
                       x, BATCH, xx, (const float*)nullptr, (float*)nullptr);
    hipLaunchKernelGGL(rbf_kernel, dim3(BATCH / BM, CSPLIT), dim3(256), 0, stream,
                       x, centres, cc, scale, node_id, xx, parts);
    hipLaunchKernelGGL(lin_kernel, dim3(OUT_TYPES / 64, BATCH / 64), dim3(256), 0, stream,
                       parts, W, bias, out);
}

// Round 2
// 182.827 us; speedup vs baseline: 36.0634x; 36.0634x over previous
//
#include <hip/hip_runtime.h>
#include <hip/hip_bf16.h>
#include <math.h>

#define BATCH 4096
#define FEAT 128
#define C_TOTAL 16384
#define OUT_TYPES 512

typedef short bf16x8 __attribute__((ext_vector_type(8)));
typedef float f32x4 __attribute__((ext_vector_type(4)));
typedef unsigned short u16;

typedef const __attribute__((address_space(1))) void cg_void;
typedef __attribute__((address_space(3))) void lds_void_t;

static __device__ __forceinline__ u16 f2bf(float f) {
    __hip_bfloat16 h = __float2bfloat16(f);
    return reinterpret_cast<u16&>(h);
}

// ---------------- prep: f32 rows -> bf16 rows + sum-of-squares (+ scale) ------
// 64 rows/block, 4 lanes/row, float4 loads -> ushort4 stores.
__global__ void prep_kernel(const float* __restrict__ src, int nrows,
                            u16* __restrict__ dstb, float* __restrict__ norm_out,
                            const float* __restrict__ ls, float* __restrict__ scale_out) {
    int t = threadIdx.x;
    int row = blockIdx.x * 64 + (t >> 2);
    int l4 = t & 3;
    if (row >= nrows) return;
    const float4* p = reinterpret_cast<const float4*>(src + (size_t)row * FEAT);
    ushort4* q = reinterpret_cast<ushort4*>(dstb + (size_t)row * FEAT);
    float s = 0.f;
#pragma unroll
    for (int i = 0; i < 8; ++i) {
        float4 v = p[i * 4 + l4];
        s += v.x * v.x + v.y * v.y + v.z * v.z + v.w * v.w;
        ushort4 h;
        h.x = f2bf(v.x); h.y = f2bf(v.y); h.z = f2bf(v.z); h.w = f2bf(v.w);
        q[i * 4 + l4] = h;
    }
    s += __shfl_xor(s, 1);
    s += __shfl_xor(s, 2);
    if (l4 == 0) {
        norm_out[row] = s;
        if (scale_out) scale_out[row] = __expf(2.f * ls[row]);
    }
}

// ---------------- rbf: MFMA bf16 pairwise -> phi -> LDS segment scatter -------
// Block: 256 thr (4 waves). BM=16 x-rows in registers; sweeps BN=64 centres/iter.
// cs staged via global_load_lds w=16, XOR-swizzled SOURCE (linear LDS dest);
// B-frag ds_read_b128 conflict-free. Epilogue: phi + guarded LDS atomic scatter
// (exp underflow => atomic essentially never executes). Deterministic partials.
#define BM 16
#define BN 64
#define CSPLIT 2
#define CCHUNK (C_TOTAL / CSPLIT) /* 8192 */
#define NIT (CCHUNK / BN)         /* 128 */

__global__ __launch_bounds__(256, 3)
void rbf_kernel(const u16* __restrict__ xb, const u16* __restrict__ cb,
                const float* __restrict__ cc, const float* __restrict__ scale,
                const int* __restrict__ node_id, const float* __restrict__ xx,
                float* __restrict__ parts) {
    __shared__ u16 cs[BN * FEAT];          // 16 KB, granule-swizzled
    __shared__ float rbf[BM][OUT_TYPES];   // 32 KB segment accumulator

    const int t = threadIdx.x;
    const int lane = t & 63;
    const int w = t >> 6;                  // wave 0..3 -> 16-col slice
    const int row0 = blockIdx.x * BM;
    const int cbase = blockIdx.y * CCHUNK;

    // zero rbf
#pragma unroll
    for (int i = 0; i < (BM * OUT_TYPES) / 256; ++i)
        (&rbf[0][0])[t + i * 256] = 0.f;

    // A fragments: lane holds x row (row0 + (lane&15)), k = (lane>>4)*8 + ks*32 .. +7
    const u16* xrow = xb + (size_t)(row0 + (lane & 15)) * FEAT + (lane >> 4) * 8;
    bf16x8 afrag[4];
#pragma unroll
    for (int ks = 0; ks < 4; ++ks)
        afrag[ks] = *reinterpret_cast<const bf16x8*>(xrow + ks * 32);

    // x norms for the 4 output rows this lane owns (C/D: row=(lane>>4)*4+j)
    float xxv[4];
#pragma unroll
    for (int j = 0; j < 4; ++j)
        xxv[j] = xx[row0 + (lane >> 4) * 4 + j];

    const int rB = w * 16 + (lane & 15);   // centre row within tile (B col)
    const int swz = rB & 7;
    const u16* csrow = cs + rB * FEAT;

    for (int it = 0; it < NIT; ++it) {
        const int c0 = cbase + it * BN;
        __syncthreads();  // cs safe to overwrite (prev readers done)
        // stage 64 centres x 128 k bf16 (16 KB): linear LDS dest, swizzled source
#pragma unroll
        for (int p = 0; p < 4; ++p) {
            int G = t + p * 256;           // granule 0..1023 (16 B each)
            int r = G >> 4;                // centre row 0..63
            int gsrc = (G & 15) ^ (r & 7); // source granule for swizzled slot
            const u16* gp = cb + (size_t)(c0 + r) * FEAT + gsrc * 8;
            __builtin_amdgcn_global_load_lds((cg_void*)gp,
                                             (lds_void_t*)((char*)cs + G * 16),
                                             16, 0, 0);
        }
        __syncthreads();  // drains vmcnt -> cs ready

        // 16x16 tile per wave over K=128
        f32x4 acc = {0.f, 0.f, 0.f, 0.f};
#pragma unroll
        for (int ks = 0; ks < 4; ++ks) {
            int gk = (ks * 4 + (lane >> 4)) ^ swz;
            bf16x8 bfrag = *reinterpret_cast<const bf16x8*>(csrow + gk * 8);
            acc = __builtin_amdgcn_mfma_f32_16x16x32_bf16(afrag[ks], bfrag, acc, 0, 0, 0);
        }

        // epilogue: phi + guarded segment scatter
        int c = c0 + w * 16 + (lane & 15);
        float ccv = cc[c];
        float sc = scale[c];
        int nid = node_id[c];
#pragma unroll
        for (int j = 0; j < 4; ++j) {
            float sqd = fmaxf(xxv[j] + ccv - 2.f * acc[j], 0.f);
            float tt = sqd * sc;
            if (tt < 88.f)  // exp(-88) flushes to 0 in f32 anyway
                atomicAdd(&rbf[(lane >> 4) * 4 + j][nid], __expf(-tt));
        }
    }
    __syncthreads();

    // deterministic per-(row-block, split) partial write [16][512]
    float* dst = parts + ((size_t)blockIdx.y * BATCH + row0) * OUT_TYPES;
#pragma unroll
    for (int i = 0; i < (BM * OUT_TYPES) / 256; ++i) {
        int idx = t + i * 256;
        dst[idx] = (&rbf[0][0])[idx];
    }
}

// ---------------- lin: out = (p0+p1) @ W^T + b (unchanged from round 1) -------
#define KC 32
__global__ __launch_bounds__(256)
void lin_kernel(const float* __restrict__ parts, const float* __restrict__ W,
                const float* __restrict__ bias, float* __restrict__ out) {
    __shared__ float as[64][KC];
    __shared__ float bs[64][KC];
    const int t = threadIdx.x;
    const int m0 = blockIdx.y * 64;
    const int n0 = blockIdx.x * 64;
    const float* p0 = parts;
    const float* p1 = parts + (size_t)BATCH * OUT_TYPES;

    const int rr = t >> 4;  // 0..15
    const int nn = t & 15;  // 0..15
    float acc[4][4] = {};

    for (int kc = 0; kc < OUT_TYPES; kc += KC) {
        __syncthreads();
#pragma unroll
        for (int j = 0; j < 2; ++j) {
            int gi = t + j * 256;
            int r = gi >> 3;
            int g = gi & 7;
            size_t off = (size_t)(m0 + r) * OUT_TYPES + kc + g * 4;
            float4 va = *reinterpret_cast<const float4*>(p0 + off);
            float4 vb = *reinterpret_cast<const float4*>(p1 + off);
            va.x += vb.x; va.y += vb.y; va.z += vb.z; va.w += vb.w;
            *reinterpret_cast<float4*>(&as[r][4 * (g ^ (r & 7))]) = va;
            float4 w = *reinterpret_cast<const float4*>(W + (size_t)(n0 + r) * OUT_TYPES + kc + g * 4);
            *reinterpret_cast<float4*>(&bs[r][4 * (g ^ (r & 7))]) = w;
        }
        __syncthreads();
#pragma unroll
        for (int g = 0; g < 8; ++g) {
            float4 a[4], b[4];
#pragma unroll
            for (int i = 0; i < 4; ++i) {
                int r = rr + 16 * i;
                a[i] = *reinterpret_cast<const float4*>(&as[r][4 * (g ^ (r & 7))]);
                int n = nn + 16 * i;
                b[i] = *reinterpret_cast<const float4*>(&bs[n][4 * (g ^ (n & 7))]);
            }
#pragma unroll
            for (int i = 0; i < 4; ++i)
#pragma unroll
                for (int j = 0; j < 4; ++j)
                    acc[i][j] += a[i].x * b[j].x + a[i].y * b[j].y +
                                 a[i].z * b[j].z + a[i].w * b[j].w;
        }
    }

#pragma unroll
    for (int i = 0; i < 4; ++i) {
        int m = m0 + rr + 16 * i;
#pragma unroll
        for (int j = 0; j < 4; ++j) {
            int n = n0 + nn + 16 * j;
            out[(size_t)m * OUT_TYPES + n] = acc[i][j] + bias[n];
        }
    }
}

// ---------------- launch ------------------------------------------------------
extern "C" void kernel_launch(void* const* d_in, const int* in_sizes, int n_in,
                              void* d_out, int out_size, void* d_ws, size_t ws_size,
                              hipStream_t stream) {
    const float* x       = (const float*)d_in[0];
    const float* centres = (const float*)d_in[1];
    const float* ls      = (const float*)d_in[2];
    const int*   node_id = (const int*)d_in[3];
    const float* W       = (const float*)d_in[4];
    const float* bias    = (const float*)d_in[5];
    float* out = (float*)d_out;

    // ws layout (bytes): parts 16 MB | xb 1 MB | cb 4 MB | cc/scale/xx
    float* parts = (float*)d_ws;                                  // 2*4096*512 f32
    char*  p     = (char*)d_ws + (size_t)2 * BATCH * OUT_TYPES * 4;
    u16*   xb    = (u16*)p;            p += (size_t)BATCH * FEAT * 2;
    u16*   cbb   = (u16*)p;            p += (size_t)C_TOTAL * FEAT * 2;
    float* cc    = (float*)p;          p += (size_t)C_TOTAL * 4;
    float* scale = (float*)p;          p += (size_t)C_TOTAL * 4;
    float* xx    = (float*)p;

    hipLaunchKernelGGL(prep_kernel, dim3(C_TOTAL / 64), dim3(256), 0, stream,
                       centres, C_TOTAL, cbb, cc, ls, scale);
    hipLaunchKernelGGL(prep_kernel, dim3(BATCH / 64), dim3(256), 0, stream,
                       x, BATCH, xb, xx, (const float*)nullptr, (float*)nullptr);
    hipLaunchKernelGGL(rbf_kernel, dim3(BATCH / BM, CSPLIT), dim3(256), 0, stream,
                       xb, cbb, cc, scale, node_id, xx, parts);
    hipLaunchKernelGGL(lin_kernel, dim3(OUT_TYPES / 64, BATCH / 64), dim3(256), 0, stream,
                       parts, W, bias, out);
}

// Round 3
// 114.546 us; speedup vs baseline: 57.5611x; 1.5961x over previous
//
#include <hip/hip_runtime.h>
#include <hip/hip_bf16.h>
#include <math.h>

#define BATCH 4096
#define FEAT 128
#define C_TOTAL 16384
#define OUT_TYPES 512

typedef short bf16x8 __attribute__((ext_vector_type(8)));
typedef float f32x4 __attribute__((ext_vector_type(4)));
typedef unsigned short u16;

typedef const __attribute__((address_space(1))) void cg_void;
typedef __attribute__((address_space(3))) void lds_void_t;

static __device__ __forceinline__ u16 f2bf(float f) {
    __hip_bfloat16 h = __float2bfloat16(f);
    return reinterpret_cast<u16&>(h);
}

// ---------------- prep: f32 rows -> bf16 rows + sum-of-squares (+ scale) ------
__global__ void prep_kernel(const float* __restrict__ src, int nrows,
                            u16* __restrict__ dstb, float* __restrict__ norm_out,
                            const float* __restrict__ ls, float* __restrict__ scale_out) {
    int t = threadIdx.x;
    int row = blockIdx.x * 64 + (t >> 2);
    int l4 = t & 3;
    if (row >= nrows) return;
    const float4* p = reinterpret_cast<const float4*>(src + (size_t)row * FEAT);
    ushort4* q = reinterpret_cast<ushort4*>(dstb + (size_t)row * FEAT);
    float s = 0.f;
#pragma unroll
    for (int i = 0; i < 8; ++i) {
        float4 v = p[i * 4 + l4];
        s += v.x * v.x + v.y * v.y + v.z * v.z + v.w * v.w;
        ushort4 h;
        h.x = f2bf(v.x); h.y = f2bf(v.y); h.z = f2bf(v.z); h.w = f2bf(v.w);
        q[i * 4 + l4] = h;
    }
    s += __shfl_xor(s, 1);
    s += __shfl_xor(s, 2);
    if (l4 == 0) {
        norm_out[row] = s;
        if (scale_out) scale_out[row] = __expf(2.f * ls[row]);
    }
}

// ---------------- conv: dst_bf16 = a (+ b optional), 8 elems/thread ----------
__global__ void conv_kernel(const float* __restrict__ a, const float* __restrict__ b,
                            u16* __restrict__ dst, int n8) {
    int i = blockIdx.x * 256 + threadIdx.x;
    if (i >= n8) return;
    const float4* pa = reinterpret_cast<const float4*>(a) + (size_t)i * 2;
    float4 v0 = pa[0], v1 = pa[1];
    if (b) {
        const float4* pb = reinterpret_cast<const float4*>(b) + (size_t)i * 2;
        float4 w0 = pb[0], w1 = pb[1];
        v0.x += w0.x; v0.y += w0.y; v0.z += w0.z; v0.w += w0.w;
        v1.x += w1.x; v1.y += w1.y; v1.z += w1.z; v1.w += w1.w;
    }
    ushort4 h0, h1;
    h0.x = f2bf(v0.x); h0.y = f2bf(v0.y); h0.z = f2bf(v0.z); h0.w = f2bf(v0.w);
    h1.x = f2bf(v1.x); h1.y = f2bf(v1.y); h1.z = f2bf(v1.z); h1.w = f2bf(v1.w);
    ushort4* q = reinterpret_cast<ushort4*>(dst) + (size_t)i * 2;
    q[0] = h0; q[1] = h1;
}

// ---------------- rbf: MFMA pairwise -> phi -> LDS segment scatter -----------
// 512 thr / 8 waves. Tile 32 rows x 128 centres/iter, K=128 in regs (A) /
// double-buffered LDS (B). One barrier per iter (T3 minimum-2-phase recipe):
// STAGE(next) issued before compute; barrier's vmcnt(0) drain is the only sync.
#define BM 32
#define BN 128
#define CSPLIT 2
#define CCHUNK (C_TOTAL / CSPLIT) /* 8192 */
#define NIT (CCHUNK / BN)         /* 64 */

__global__ __launch_bounds__(512)
void rbf_kernel(const u16* __restrict__ xb, const u16* __restrict__ cb,
                const float* __restrict__ cc, const float* __restrict__ scale,
                const int* __restrict__ node_id, const float* __restrict__ xx,
                float* __restrict__ parts) {
    __shared__ u16 cs[2][BN * FEAT];       // 2 x 32 KB, granule-swizzled
    __shared__ float rbf[BM][OUT_TYPES];   // 64 KB segment accumulator

    const int t = threadIdx.x;
    const int lane = t & 63;
    const int w = t >> 6;
    const int wr = w >> 2;                 // 0..1  row-group
    const int wc = w & 3;                  // 0..3  col-group
    const int row0 = blockIdx.x * BM;
    const int cbase = blockIdx.y * CCHUNK;

    // stage buffer 0 (linear LDS dest, swizzled global source — m173 pattern)
#pragma unroll
    for (int p = 0; p < 4; ++p) {
        int G = t + p * 512;               // granule 0..2047 (16 B)
        int r = G >> 4;                    // centre row 0..127
        int gsrc = (G & 15) ^ (r & 7);
        __builtin_amdgcn_global_load_lds(
            (cg_void*)(cb + (size_t)(cbase + r) * FEAT + gsrc * 8),
            (lds_void_t*)((char*)cs[0] + G * 16), 16, 0, 0);
    }

    // zero rbf
    f32x4* rb4 = reinterpret_cast<f32x4*>(&rbf[0][0]);
#pragma unroll
    for (int i = 0; i < 8; ++i) rb4[t + i * 512] = f32x4{0.f, 0.f, 0.f, 0.f};

    // A-frags (held entire kernel) + x norms
    const u16* xrow = xb + (size_t)(row0 + wr * 16 + (lane & 15)) * FEAT + (lane >> 4) * 8;
    bf16x8 afrag[4];
#pragma unroll
    for (int ks = 0; ks < 4; ++ks)
        afrag[ks] = *reinterpret_cast<const bf16x8*>(xrow + ks * 32);
    float xxv[4];
#pragma unroll
    for (int j = 0; j < 4; ++j)
        xxv[j] = xx[row0 + wr * 16 + (lane >> 4) * 4 + j];

    const int rB0 = wc * 32 + (lane & 15);
    __syncthreads();

    int cur = 0;
    for (int it = 0; it < NIT; ++it) {
        const int c0 = cbase + it * BN;
        if (it + 1 < NIT) {                // issue next tile FIRST
#pragma unroll
            for (int p = 0; p < 4; ++p) {
                int G = t + p * 512;
                int r = G >> 4;
                int gsrc = (G & 15) ^ (r & 7);
                __builtin_amdgcn_global_load_lds(
                    (cg_void*)(cb + (size_t)(c0 + BN + r) * FEAT + gsrc * 8),
                    (lds_void_t*)((char*)cs[cur ^ 1] + G * 16), 16, 0, 0);
            }
        }
        const u16* base = cs[cur];
#pragma unroll
        for (int fq = 0; fq < 2; ++fq) {
            const int rB = rB0 + fq * 16;
            const int swz = rB & 7;
            const u16* brow = base + rB * FEAT;
            f32x4 acc = {0.f, 0.f, 0.f, 0.f};
#pragma unroll
            for (int ks = 0; ks < 4; ++ks) {
                int gk = (ks * 4 + (lane >> 4)) ^ swz;
                bf16x8 bfrag = *reinterpret_cast<const bf16x8*>(brow + gk * 8);
                acc = __builtin_amdgcn_mfma_f32_16x16x32_bf16(afrag[ks], bfrag, acc, 0, 0, 0);
            }
            // epilogue: phi + guarded segment scatter (underflow => no atomic)
            int c = c0 + rB;
            float ccv = cc[c], sc = scale[c];
            int nid = node_id[c];
#pragma unroll
            for (int j = 0; j < 4; ++j) {
                float sqd = fmaxf(xxv[j] + ccv - 2.f * acc[j], 0.f);
                float tt = sqd * sc;
                if (tt < 88.f)
                    atomicAdd(&rbf[wr * 16 + (lane >> 4) * 4 + j][nid], __expf(-tt));
            }
        }
        __syncthreads();   // drains vmcnt(0): next buf staged; guards cs reuse
        cur ^= 1;
    }

    // deterministic per-(row-block, split) partial [32][512]
    float4* dst = reinterpret_cast<float4*>(parts + ((size_t)blockIdx.y * BATCH + row0) * OUT_TYPES);
    const float4* src = reinterpret_cast<const float4*>(&rbf[0][0]);
#pragma unroll
    for (int i = 0; i < 8; ++i) dst[t + i * 512] = src[t + i * 512];
}

// ---------------- lin: out = psum_bf16 @ Wb^T + b via MFMA --------------------
// 64x64 tile, K=512 in 4 double-buffered chunks of 128, 8 waves (2x16 sub-tiles)
#define LKC 128
__global__ __launch_bounds__(512)
void lin_kernel(const u16* __restrict__ pa, const u16* __restrict__ wb,
                const float* __restrict__ bias, float* __restrict__ out) {
    __shared__ u16 as[2][64 * LKC];   // 16 KB each
    __shared__ u16 bs[2][64 * LKC];

    const int t = threadIdx.x;
    const int lane = t & 63;
    const int w = t >> 6;
    const int rw = (w & 3) * 16;      // wave row offset
    const int cw = (w >> 2) * 32;     // wave col offset (2 frags)
    const int m0 = blockIdx.y * 64;
    const int n0 = blockIdx.x * 64;

    // chunk 0
#pragma unroll
    for (int p = 0; p < 2; ++p) {
        int G = t + p * 512;          // 1024 granules per array
        int r = G >> 4;               // row 0..63 (16 granules of 16B per row)
        int gsrc = (G & 15) ^ (r & 7);
        __builtin_amdgcn_global_load_lds(
            (cg_void*)(pa + (size_t)(m0 + r) * OUT_TYPES + gsrc * 8),
            (lds_void_t*)((char*)as[0] + G * 16), 16, 0, 0);
        __builtin_amdgcn_global_load_lds(
            (cg_void*)(wb + (size_t)(n0 + r) * OUT_TYPES + gsrc * 8),
            (lds_void_t*)((char*)bs[0] + G * 16), 16, 0, 0);
    }

    f32x4 acc0 = {0.f, 0.f, 0.f, 0.f}, acc1 = {0.f, 0.f, 0.f, 0.f};
    __syncthreads();

    int cur = 0;
#pragma unroll
    for (int ck = 0; ck < 4; ++ck) {
        if (ck + 1 < 4) {
#pragma unroll
            for (int p = 0; p < 2; ++p) {
                int G = t + p * 512;
                int r = G >> 4;
                int gsrc = (G & 15) ^ (r & 7);
                size_t koff = (size_t)(ck + 1) * LKC + gsrc * 8;
                __builtin_amdgcn_global_load_lds(
                    (cg_void*)(pa + (size_t)(m0 + r) * OUT_TYPES + koff),
                    (lds_void_t*)((char*)as[cur ^ 1] + G * 16), 16, 0, 0);
                __builtin_amdgcn_global_load_lds(
                    (cg_void*)(wb + (size_t)(n0 + r) * OUT_TYPES + koff),
                    (lds_void_t*)((char*)bs[cur ^ 1] + G * 16), 16, 0, 0);
            }
        }
        const u16* ab = as[cur];
        const u16* bb = bs[cur];
        const int rA = rw + (lane & 15);
        const int swa = rA & 7;
        const u16* arow = ab + rA * LKC;
        const int rB0 = cw + (lane & 15);
        const int rB1 = rB0 + 16;
        const u16* brow0 = bb + rB0 * LKC;
        const u16* brow1 = bb + rB1 * LKC;
        const int swb0 = rB0 & 7;       // == swb1
#pragma unroll
        for (int ks = 0; ks < 4; ++ks) {
            int q = ks * 4 + (lane >> 4);
            bf16x8 af = *reinterpret_cast<const bf16x8*>(arow + (q ^ swa) * 8);
            bf16x8 b0 = *reinterpret_cast<const bf16x8*>(brow0 + (q ^ swb0) * 8);
            bf16x8 b1 = *reinterpret_cast<const bf16x8*>(brow1 + (q ^ swb0) * 8);
            acc0 = __builtin_amdgcn_mfma_f32_16x16x32_bf16(af, b0, acc0, 0, 0, 0);
            acc1 = __builtin_amdgcn_mfma_f32_16x16x32_bf16(af, b1, acc1, 0, 0, 0);
        }
        __syncthreads();
        cur ^= 1;
    }

    const int n_a = n0 + cw + (lane & 15);
    const int n_b = n_a + 16;
    const float bva = bias[n_a];
    const float bvb = bias[n_b];
#pragma unroll
    for (int j = 0; j < 4; ++j) {
        int m = m0 + rw + (lane >> 4) * 4 + j;
        out[(size_t)m * OUT_TYPES + n_a] = acc0[j] + bva;
        out[(size_t)m * OUT_TYPES + n_b] = acc1[j] + bvb;
    }
}

// ---------------- launch ------------------------------------------------------
extern "C" void kernel_launch(void* const* d_in, const int* in_sizes, int n_in,
                              void* d_out, int out_size, void* d_ws, size_t ws_size,
                              hipStream_t stream) {
    const float* x       = (const float*)d_in[0];
    const float* centres = (const float*)d_in[1];
    const float* ls      = (const float*)d_in[2];
    const int*   node_id = (const int*)d_in[3];
    const float* W       = (const float*)d_in[4];
    const float* bias    = (const float*)d_in[5];
    float* out = (float*)d_out;

    // ws: parts 16MB | xb 1MB | cbb 4MB | cc 64KB | scale 64KB | xx 16KB
    //     | wb 512KB | psum 4MB
    char* p = (char*)d_ws;
    float* parts = (float*)p;  p += (size_t)2 * BATCH * OUT_TYPES * 4;
    u16*   xb    = (u16*)p;    p += (size_t)BATCH * FEAT * 2;
    u16*   cbb   = (u16*)p;    p += (size_t)C_TOTAL * FEAT * 2;
    float* cc    = (float*)p;  p += (size_t)C_TOTAL * 4;
    float* scale = (float*)p;  p += (size_t)C_TOTAL * 4;
    float* xx    = (float*)p;  p += (size_t)BATCH * 4;
    u16*   wbuf  = (u16*)p;    p += (size_t)OUT_TYPES * OUT_TYPES * 2;
    u16*   psum  = (u16*)p;

    hipLaunchKernelGGL(prep_kernel, dim3(C_TOTAL / 64), dim3(256), 0, stream,
                       centres, C_TOTAL, cbb, cc, ls, scale);
    hipLaunchKernelGGL(prep_kernel, dim3(BATCH / 64), dim3(256), 0, stream,
                       x, BATCH, xb, xx, (const float*)nullptr, (float*)nullptr);
    hipLaunchKernelGGL(conv_kernel, dim3(OUT_TYPES * OUT_TYPES / 8 / 256), dim3(256), 0, stream,
                       W, (const float*)nullptr, wbuf, OUT_TYPES * OUT_TYPES / 8);
    hipLaunchKernelGGL(rbf_kernel, dim3(BATCH / BM, CSPLIT), dim3(512), 0, stream,
                       xb, cbb, cc, scale, node_id, xx, parts);
    hipLaunchKernelGGL(conv_kernel, dim3(BATCH * OUT_TYPES / 8 / 256), dim3(256), 0, stream,
                       parts, parts + (size_t)BATCH * OUT_TYPES, psum, BATCH * OUT_TYPES / 8);
    hipLaunchKernelGGL(lin_kernel, dim3(OUT_TYPES / 64, BATCH / 64), dim3(512), 0, stream,
                       psum, wbuf, bias, out);
}

// Round 4
// 49.441 us; speedup vs baseline: 133.3576x; 2.3168x over previous
//
#include <hip/hip_runtime.h>
#include <hip/hip_bf16.h>
#include <math.h>

#define BATCH 4096
#define FEAT 128
#define C_TOTAL 16384
#define OUT_TYPES 512

typedef short bf16x8 __attribute__((ext_vector_type(8)));
typedef float f32x4 __attribute__((ext_vector_type(4)));
typedef unsigned short u16;

typedef const __attribute__((address_space(1))) void cg_void;
typedef __attribute__((address_space(3))) void lds_void_t;

static __device__ __forceinline__ u16 f2bf(float f) {
    __hip_bfloat16 h = __float2bfloat16(f);
    return reinterpret_cast<u16&>(h);
}

// ---------------- prologue: out=bias bcast | centres prep | x prep -----------
// blocks 0..2047: out init; 2048..2303: centre rows; 2304..2367: x rows.
__global__ void prologue_kernel(const float* __restrict__ x, const float* __restrict__ centres,
                                const float* __restrict__ ls, const float* __restrict__ bias,
                                u16* __restrict__ xb, u16* __restrict__ cbb,
                                float* __restrict__ cc, float* __restrict__ scale,
                                float* __restrict__ hc, float* __restrict__ xx,
                                float* __restrict__ xh, float* __restrict__ out) {
    const int b = blockIdx.x;
    const int t = threadIdx.x;
    if (b < 2048) {                       // out[m][n] = bias[n], 8 MB
        int i = b * 256 + t;              // float4 index
        float4 bv = reinterpret_cast<const float4*>(bias)[i & 127];
        reinterpret_cast<float4*>(out)[i] = bv;
        return;
    }
    const bool is_c = (b < 2048 + 256);
    const int row = (is_c ? (b - 2048) : (b - 2304)) * 64 + (t >> 2);
    const int l4 = t & 3;
    const float* src = is_c ? centres : x;
    u16* dstb = is_c ? cbb : xb;
    const float4* p = reinterpret_cast<const float4*>(src + (size_t)row * FEAT);
    ushort4* q = reinterpret_cast<ushort4*>(dstb + (size_t)row * FEAT);
    float s = 0.f;
#pragma unroll
    for (int i = 0; i < 8; ++i) {
        float4 v = p[i * 4 + l4];
        s += v.x * v.x + v.y * v.y + v.z * v.z + v.w * v.w;
        ushort4 h;
        h.x = f2bf(v.x); h.y = f2bf(v.y); h.z = f2bf(v.z); h.w = f2bf(v.w);
        q[i * 4 + l4] = h;
    }
    s += __shfl_xor(s, 1);
    s += __shfl_xor(s, 2);
    if (l4 == 0) {
        if (is_c) {
            cc[row] = s;
            scale[row] = __expf(2.f * ls[row]);
            // threshold: sqd*scale < 96  <=>  d > 0.5*cc - 48/scale + 0.5*xx
            hc[row] = 0.5f * s - 48.f * __expf(-2.f * ls[row]);
        } else {
            xx[row] = s;
            xh[row] = 0.5f * s;
        }
    }
}

// ---------------- rbf: A-in-regs MFMA + threshold epilogue -------------------
// 512 thr / 8 waves. Wave-tile 128 rows x 16 cols; block tile 128x128 per iter.
// A (128x128 bf16) lives in 128 VGPRs for the whole kernel; B double-buffered
// in LDS (2x32 KB), staged via global_load_lds w=16 with pre-swizzled source.
// Epilogue: 1 sub+cmp per C-element; rare branch (phi representable in f32)
// does the full phi + rank-1 update of out with W column nid.
#define BM 128
#define BN 128
#define CSPLIT 8
#define CCHUNK (C_TOTAL / CSPLIT) /* 2048 */
#define NIT (CCHUNK / BN)         /* 16 */

__global__ __launch_bounds__(512, 2)
void rbf_kernel(const u16* __restrict__ xb, const u16* __restrict__ cb,
                const float* __restrict__ hc, const float* __restrict__ xh,
                const float* __restrict__ cc, const float* __restrict__ scale,
                const int* __restrict__ node_id, const float* __restrict__ xx,
                const float* __restrict__ W, float* __restrict__ out) {
    __shared__ u16 cs[2][BN * FEAT];      // 2 x 32 KB, granule-swizzled

    const int t = threadIdx.x;
    const int lane = t & 63;
    const int w = t >> 6;                 // col-group 0..7
    const int row0 = blockIdx.x * BM;
    const int cbase = blockIdx.y * CCHUNK;

    // stage buffer 0 (linear LDS dest, swizzled global source)
#pragma unroll
    for (int p = 0; p < 4; ++p) {
        int G = t + p * 512;              // granule 0..2047 (16 B)
        int r = G >> 4;
        int gsrc = (G & 15) ^ (r & 7);
        __builtin_amdgcn_global_load_lds(
            (cg_void*)(cb + (size_t)(cbase + r) * FEAT + gsrc * 8),
            (lds_void_t*)((char*)cs[0] + G * 16), 16, 0, 0);
    }

    // A fragments: 8 m-frags x 4 k-slices, held in registers all kernel
    bf16x8 af[8][4];
#pragma unroll
    for (int m = 0; m < 8; ++m) {
        const u16* xrow = xb + (size_t)(row0 + m * 16 + (lane & 15)) * FEAT + (lane >> 4) * 8;
#pragma unroll
        for (int ks = 0; ks < 4; ++ks)
            af[m][ks] = *reinterpret_cast<const bf16x8*>(xrow + ks * 32);
    }
    // xh for the 32 output rows this lane owns
    float xhv[8][4];
#pragma unroll
    for (int m = 0; m < 8; ++m)
#pragma unroll
        for (int j = 0; j < 4; ++j)
            xhv[m][j] = xh[row0 + m * 16 + (lane >> 4) * 4 + j];

    const int rB = w * 16 + (lane & 15);  // centre row within tile
    const int swz = rB & 7;

    __syncthreads();                      // buffer 0 staged (vmcnt drain)

    int cur = 0;
    for (int it = 0; it < NIT; ++it) {
        const int c0 = cbase + it * BN;
        if (it + 1 < NIT) {               // issue next-tile loads first
#pragma unroll
            for (int p = 0; p < 4; ++p) {
                int G = t + p * 512;
                int r = G >> 4;
                int gsrc = (G & 15) ^ (r & 7);
                __builtin_amdgcn_global_load_lds(
                    (cg_void*)(cb + (size_t)(c0 + BN + r) * FEAT + gsrc * 8),
                    (lds_void_t*)((char*)cs[cur ^ 1] + G * 16), 16, 0, 0);
            }
        }

        const u16* brow = cs[cur] + rB * FEAT;
        f32x4 acc[8];
#pragma unroll
        for (int m = 0; m < 8; ++m) acc[m] = f32x4{0.f, 0.f, 0.f, 0.f};
#pragma unroll
        for (int ks = 0; ks < 4; ++ks) {
            int gk = (ks * 4 + (lane >> 4)) ^ swz;
            bf16x8 bf = *reinterpret_cast<const bf16x8*>(brow + gk * 8);
#pragma unroll
            for (int m = 0; m < 8; ++m)
                acc[m] = __builtin_amdgcn_mfma_f32_16x16x32_bf16(af[m][ks], bf, acc[m], 0, 0, 0);
        }

        // epilogue: d - xh > hc  <=>  sqd*scale < 96 (phi >= ~2e-42)
        const int c = c0 + rB;
        const float hcv = hc[c];
#pragma unroll
        for (int m = 0; m < 8; ++m) {
#pragma unroll
            for (int j = 0; j < 4; ++j) {
                if (__builtin_expect(acc[m][j] - xhv[m][j] > hcv, 0)) {
                    // rare path: full phi + rank-1 update out[row,:] += phi*W[:,nid]
                    const int row = row0 + m * 16 + (lane >> 4) * 4 + j;
                    float sqd = fmaxf(xx[row] + cc[c] - 2.f * acc[m][j], 0.f);
                    float phi = __expf(-sqd * scale[c]);
                    int nid = node_id[c];
                    float* orow = out + (size_t)row * OUT_TYPES;
                    const float* wcol = W + nid;
                    for (int n = 0; n < OUT_TYPES; ++n)
                        atomicAdd(&orow[n], phi * wcol[(size_t)n * OUT_TYPES]);
                }
            }
        }
        __syncthreads();                  // next buffer staged; cs reuse safe
        cur ^= 1;
    }
}

// ---------------- launch ------------------------------------------------------
extern "C" void kernel_launch(void* const* d_in, const int* in_sizes, int n_in,
                              void* d_out, int out_size, void* d_ws, size_t ws_size,
                              hipStream_t stream) {
    const float* x       = (const float*)d_in[0];
    const float* centres = (const float*)d_in[1];
    const float* ls      = (const float*)d_in[2];
    const int*   node_id = (const int*)d_in[3];
    const float* W       = (const float*)d_in[4];
    const float* bias    = (const float*)d_in[5];
    float* out = (float*)d_out;

    // ws: xb 1MB | cbb 4MB | cc 64KB | scale 64KB | hc 64KB | xx 16KB | xh 16KB
    char* p = (char*)d_ws;
    u16*   xb    = (u16*)p;    p += (size_t)BATCH * FEAT * 2;
    u16*   cbb   = (u16*)p;    p += (size_t)C_TOTAL * FEAT * 2;
    float* cc    = (float*)p;  p += (size_t)C_TOTAL * 4;
    float* scale = (float*)p;  p += (size_t)C_TOTAL * 4;
    float* hc    = (float*)p;  p += (size_t)C_TOTAL * 4;
    float* xx    = (float*)p;  p += (size_t)BATCH * 4;
    float* xh    = (float*)p;  p += (size_t)BATCH * 4;

    hipLaunchKernelGGL(prologue_kernel, dim3(2048 + 256 + 64), dim3(256), 0, stream,
                       x, centres, ls, bias, xb, cbb, cc, scale, hc, xx, xh, out);
    hipLaunchKernelGGL(rbf_kernel, dim3(BATCH / BM, CSPLIT), dim3(512), 0, stream,
                       xb, cbb, hc, xh, cc, scale, node_id, xx, W, out);
}

// Round 5
// 46.907 us; speedup vs baseline: 140.5624x; 1.0540x over previous
//
#include <hip/hip_runtime.h>
#include <hip/hip_bf16.h>
#include <math.h>

#define BATCH 4096
#define FEAT 128
#define C_TOTAL 16384
#define OUT_TYPES 512

typedef short bf16x8 __attribute__((ext_vector_type(8)));
typedef float f32x4 __attribute__((ext_vector_type(4)));
typedef unsigned short u16;

typedef const __attribute__((address_space(1))) void cg_void;
typedef __attribute__((address_space(3))) void lds_void_t;

static __device__ __forceinline__ u16 f2bf(float f) {
    __hip_bfloat16 h = __float2bfloat16(f);
    return reinterpret_cast<u16&>(h);
}

// ---------------- prologue: out=bias bcast | centres prep | x prep -----------
__global__ void prologue_kernel(const float* __restrict__ x, const float* __restrict__ centres,
                                const float* __restrict__ ls, const float* __restrict__ bias,
                                u16* __restrict__ xb, u16* __restrict__ cbb,
                                float* __restrict__ cc, float* __restrict__ scale,
                                float* __restrict__ hc, float* __restrict__ xx,
                                float* __restrict__ xh, float* __restrict__ out) {
    const int b = blockIdx.x;
    const int t = threadIdx.x;
    if (b < 2048) {                       // out[m][n] = bias[n], 8 MB
        int i = b * 256 + t;              // float4 index
        float4 bv = reinterpret_cast<const float4*>(bias)[i & 127];
        reinterpret_cast<float4*>(out)[i] = bv;
        return;
    }
    const bool is_c = (b < 2048 + 256);
    const int row = (is_c ? (b - 2048) : (b - 2304)) * 64 + (t >> 2);
    const int l4 = t & 3;
    const float* src = is_c ? centres : x;
    u16* dstb = is_c ? cbb : xb;
    const float4* p = reinterpret_cast<const float4*>(src + (size_t)row * FEAT);
    ushort4* q = reinterpret_cast<ushort4*>(dstb + (size_t)row * FEAT);
    float s = 0.f;
#pragma unroll
    for (int i = 0; i < 8; ++i) {
        float4 v = p[i * 4 + l4];
        s += v.x * v.x + v.y * v.y + v.z * v.z + v.w * v.w;
        ushort4 h;
        h.x = f2bf(v.x); h.y = f2bf(v.y); h.z = f2bf(v.z); h.w = f2bf(v.w);
        q[i * 4 + l4] = h;
    }
    s += __shfl_xor(s, 1);
    s += __shfl_xor(s, 2);
    if (l4 == 0) {
        if (is_c) {
            cc[row] = s;
            scale[row] = __expf(2.f * ls[row]);
            // threshold: sqd*scale < 96  <=>  d > 0.5*cc - 48/scale + 0.5*xx
            hc[row] = 0.5f * s - 48.f * __expf(-2.f * ls[row]);
        } else {
            xx[row] = s;
            xh[row] = 0.5f * s;
        }
    }
}

// ---------------- rbf: A-in-regs MFMA + threshold epilogue -------------------
// 256 thr / 4 waves; 2 blocks/CU (two independent barrier groups per CU so one
// block's MFMAs cover the other's stage/drain). Wave-tile 128 rows x 16 cols;
// block tile 128x64/iter. A (128x128 bf16) in 128 VGPRs for the whole kernel;
// B double-buffered LDS 2x16 KB via global_load_lds w=16, pre-swizzled source.
// Epilogue: 1 sub+cmp per C elem; rare branch does full phi + rank-1 update.
#define BM 128
#define BN 64
#define CSPLIT 16
#define CCHUNK (C_TOTAL / CSPLIT) /* 1024 */
#define NIT (CCHUNK / BN)         /* 16 */

__global__ __launch_bounds__(256, 2)
void rbf_kernel(const u16* __restrict__ xb, const u16* __restrict__ cb,
                const float* __restrict__ hc, const float* __restrict__ xh,
                const float* __restrict__ cc, const float* __restrict__ scale,
                const int* __restrict__ node_id, const float* __restrict__ xx,
                const float* __restrict__ W, float* __restrict__ out) {
    __shared__ u16 cs[2][BN * FEAT];      // 2 x 16 KB, granule-swizzled

    const int t = threadIdx.x;
    const int lane = t & 63;
    const int w = t >> 6;                 // col-group 0..3
    const int row0 = blockIdx.x * BM;
    const int cbase = blockIdx.y * CCHUNK;

    // stage buffer 0 (linear LDS dest, swizzled global source)
#pragma unroll
    for (int p = 0; p < 4; ++p) {
        int G = t + p * 256;              // granule 0..1023 (16 B)
        int r = G >> 4;
        int gsrc = (G & 15) ^ (r & 7);
        __builtin_amdgcn_global_load_lds(
            (cg_void*)(cb + (size_t)(cbase + r) * FEAT + gsrc * 8),
            (lds_void_t*)((char*)cs[0] + G * 16), 16, 0, 0);
    }

    // A fragments: 8 m-frags x 4 k-slices, held in registers all kernel
    bf16x8 af[8][4];
#pragma unroll
    for (int m = 0; m < 8; ++m) {
        const u16* xrow = xb + (size_t)(row0 + m * 16 + (lane & 15)) * FEAT + (lane >> 4) * 8;
#pragma unroll
        for (int ks = 0; ks < 4; ++ks)
            af[m][ks] = *reinterpret_cast<const bf16x8*>(xrow + ks * 32);
    }
    // xh for the 32 output rows this lane owns
    float xhv[8][4];
#pragma unroll
    for (int m = 0; m < 8; ++m)
#pragma unroll
        for (int j = 0; j < 4; ++j)
            xhv[m][j] = xh[row0 + m * 16 + (lane >> 4) * 4 + j];

    const int rB = w * 16 + (lane & 15);  // centre row within tile
    const int swz = rB & 7;

    __syncthreads();                      // buffer 0 staged (vmcnt drain)

    int cur = 0;
    for (int it = 0; it < NIT; ++it) {
        const int c0 = cbase + it * BN;
        if (it + 1 < NIT) {               // issue next-tile loads first
#pragma unroll
            for (int p = 0; p < 4; ++p) {
                int G = t + p * 256;
                int r = G >> 4;
                int gsrc = (G & 15) ^ (r & 7);
                __builtin_amdgcn_global_load_lds(
                    (cg_void*)(cb + (size_t)(c0 + BN + r) * FEAT + gsrc * 8),
                    (lds_void_t*)((char*)cs[cur ^ 1] + G * 16), 16, 0, 0);
            }
        }

        const u16* brow = cs[cur] + rB * FEAT;
        f32x4 acc[8];
#pragma unroll
        for (int m = 0; m < 8; ++m) acc[m] = f32x4{0.f, 0.f, 0.f, 0.f};
        __builtin_amdgcn_s_setprio(1);
#pragma unroll
        for (int ks = 0; ks < 4; ++ks) {
            int gk = (ks * 4 + (lane >> 4)) ^ swz;
            bf16x8 bf = *reinterpret_cast<const bf16x8*>(brow + gk * 8);
#pragma unroll
            for (int m = 0; m < 8; ++m)
                acc[m] = __builtin_amdgcn_mfma_f32_16x16x32_bf16(af[m][ks], bf, acc[m], 0, 0, 0);
        }
        __builtin_amdgcn_s_setprio(0);

        // epilogue: d - xh > hc  <=>  sqd*scale < 96 (phi >= ~2e-42)
        const int c = c0 + rB;
        const float hcv = hc[c];
#pragma unroll
        for (int m = 0; m < 8; ++m) {
#pragma unroll
            for (int j = 0; j < 4; ++j) {
                if (__builtin_expect(acc[m][j] - xhv[m][j] > hcv, 0)) {
                    // rare path: full phi + rank-1 update out[row,:] += phi*W[:,nid]
                    const int row = row0 + m * 16 + (lane >> 4) * 4 + j;
                    float sqd = fmaxf(xx[row] + cc[c] - 2.f * acc[m][j], 0.f);
                    float phi = __expf(-sqd * scale[c]);
                    int nid = node_id[c];
                    float* orow = out + (size_t)row * OUT_TYPES;
                    const float* wcol = W + nid;
                    for (int n = 0; n < OUT_TYPES; ++n)
                        atomicAdd(&orow[n], phi * wcol[(size_t)n * OUT_TYPES]);
                }
            }
        }
        __syncthreads();                  // next buffer staged; cs reuse safe
        cur ^= 1;
    }
}

// ---------------- launch ------------------------------------------------------
extern "C" void kernel_launch(void* const* d_in, const int* in_sizes, int n_in,
                              void* d_out, int out_size, void* d_ws, size_t ws_size,
                              hipStream_t stream) {
    const float* x       = (const float*)d_in[0];
    const float* centres = (const float*)d_in[1];
    const float* ls      = (const float*)d_in[2];
    const int*   node_id = (const int*)d_in[3];
    const float* W       = (const float*)d_in[4];
    const float* bias    = (const float*)d_in[5];
    float* out = (float*)d_out;

    // ws: xb 1MB | cbb 4MB | cc 64KB | scale 64KB | hc 64KB | xx 16KB | xh 16KB
    char* p = (char*)d_ws;
    u16*   xb    = (u16*)p;    p += (size_t)BATCH * FEAT * 2;
    u16*   cbb   = (u16*)p;    p += (size_t)C_TOTAL * FEAT * 2;
    float* cc    = (float*)p;  p += (size_t)C_TOTAL * 4;
    float* scale = (float*)p;  p += (size_t)C_TOTAL * 4;
    float* hc    = (float*)p;  p += (size_t)C_TOTAL * 4;
    float* xx    = (float*)p;  p += (size_t)BATCH * 4;
    float* xh    = (float*)p;  p += (size_t)BATCH * 4;

    hipLaunchKernelGGL(prologue_kernel, dim3(2048 + 256 + 64), dim3(256), 0, stream,
                       x, centres, ls, bias, xb, cbb, cc, scale, hc, xx, xh, out);
    hipLaunchKernelGGL(rbf_kernel, dim3(BATCH / BM, CSPLIT), dim3(256), 0, stream,
                       xb, cbb, hc, xh, cc, scale, node_id, xx, W, out);
}

// Round 6
// 35.007 us; speedup vs baseline: 188.3423x; 1.3399x over previous
//
#include <hip/hip_runtime.h>
#include <hip/hip_bf16.h>
#include <math.h>

#define BATCH 4096
#define FEAT 128
#define C_TOTAL 16384
#define OUT_TYPES 512

typedef short bf16x8 __attribute__((ext_vector_type(8)));
typedef float f32x4 __attribute__((ext_vector_type(4)));
typedef unsigned short u16;

typedef const __attribute__((address_space(1))) void cg_void;
typedef __attribute__((address_space(3))) void lds_void_t;

static __device__ __forceinline__ u16 f2bf(float f) {
    __hip_bfloat16 h = __float2bfloat16(f);
    return reinterpret_cast<u16&>(h);
}

// ---------------- prologue: out=bias bcast | centres prep | x prep -----------
__global__ void prologue_kernel(const float* __restrict__ x, const float* __restrict__ centres,
                                const float* __restrict__ ls, const float* __restrict__ bias,
                                u16* __restrict__ xb, u16* __restrict__ cbb,
                                float* __restrict__ cc, float* __restrict__ scale,
                                float* __restrict__ hc, float* __restrict__ xx,
                                float* __restrict__ out) {
    const int b = blockIdx.x;
    const int t = threadIdx.x;
    if (b < 2048) {                       // out[m][n] = bias[n], 8 MB
        int i = b * 256 + t;              // float4 index
        float4 bv = reinterpret_cast<const float4*>(bias)[i & 127];
        reinterpret_cast<float4*>(out)[i] = bv;
        return;
    }
    const bool is_c = (b < 2048 + 256);
    const int row = (is_c ? (b - 2048) : (b - 2304)) * 64 + (t >> 2);
    const int l4 = t & 3;
    const float* src = is_c ? centres : x;
    u16* dstb = is_c ? cbb : xb;
    const float4* p = reinterpret_cast<const float4*>(src + (size_t)row * FEAT);
    ushort4* q = reinterpret_cast<ushort4*>(dstb + (size_t)row * FEAT);
    float s = 0.f;
#pragma unroll
    for (int i = 0; i < 8; ++i) {
        float4 v = p[i * 4 + l4];
        s += v.x * v.x + v.y * v.y + v.z * v.z + v.w * v.w;
        ushort4 h;
        h.x = f2bf(v.x); h.y = f2bf(v.y); h.z = f2bf(v.z); h.w = f2bf(v.w);
        q[i * 4 + l4] = h;
    }
    s += __shfl_xor(s, 1);
    s += __shfl_xor(s, 2);
    if (l4 == 0) {
        if (is_c) {
            cc[row] = s;
            scale[row] = __expf(2.f * ls[row]);
            // threshold: sqd*scale < 96  <=>  d - 0.5*xx > 0.5*cc - 48/scale
            hc[row] = 0.5f * s - 48.f * __expf(-2.f * ls[row]);
        } else {
            xx[row] = s;
        }
    }
}

// ---------------- rare path: exact phi + rank-1 update (never fires on this
// data; correct if it does). noinline keeps 128 call sites tiny. -------------
__device__ __noinline__ void rare_path(float a0, float a1, float a2, float a3,
                                       int c, int rowb,
                                       const float* xx, const float* cc,
                                       const float* scale, const int* node_id,
                                       const float* W, float* out) {
    float ccv = cc[c], sv = scale[c];
    int nid = node_id[c];
    float av[4] = {a0, a1, a2, a3};
#pragma unroll
    for (int j = 0; j < 4; ++j) {
        float sqd = fmaxf(xx[rowb + j] + ccv - 2.f * av[j], 0.f);
        float tt = sqd * sv;
        if (tt < 96.f) {
            float phi = __expf(-tt);
            float* orow = out + (size_t)(rowb + j) * OUT_TYPES;
            const float* wc = W + nid;
            for (int n = 0; n < OUT_TYPES; ++n)
                atomicAdd(&orow[n], phi * wc[(size_t)n * OUT_TYPES]);
        }
    }
}

// ---------------- rbf: A-in-regs MFMA, counted-vmcnt pipeline ----------------
// 256 thr / 4 waves, 2 blocks/CU. Wave-tile 128 rows x 16 cols; 128x64/iter.
// A (128x128 bf16) in 128 VGPRs; B triple-buffered LDS (3x16 KB), depth-2
// prefetch, s_waitcnt vmcnt(4) + raw s_barrier per iter (never drain to 0
// mid-loop). Loop body has ZERO global loads: all epilogue metadata (hcv,
// xh4min) preloaded to registers, so no in-order-vmcnt serialization.
#define BM 128
#define BN 64
#define CSPLIT 16
#define CCHUNK (C_TOTAL / CSPLIT) /* 1024 */
#define NIT (CCHUNK / BN)         /* 16 */

__global__ __launch_bounds__(256, 2)
void rbf_kernel(const u16* __restrict__ xb, const u16* __restrict__ cb,
                const float* __restrict__ hc, const float* __restrict__ cc,
                const float* __restrict__ scale, const int* __restrict__ node_id,
                const float* __restrict__ xx, const float* __restrict__ W,
                float* __restrict__ out) {
    __shared__ u16 cs[3][BN * FEAT];      // 3 x 16 KB, granule-swizzled

    const int t = threadIdx.x;
    const int lane = t & 63;
    const int w = t >> 6;                 // col-group 0..3
    const int row0 = blockIdx.x * BM;
    const int cbase = blockIdx.y * CCHUNK;
    const int rB = w * 16 + (lane & 15);  // centre row within tile
    const int swz = rB & 7;

    // ---- setup: ALL vmem consumed here, before staging begins ----
    bf16x8 af[8][4];
#pragma unroll
    for (int m = 0; m < 8; ++m) {
        const u16* xrow = xb + (size_t)(row0 + m * 16 + (lane & 15)) * FEAT + (lane >> 4) * 8;
#pragma unroll
        for (int ks = 0; ks < 4; ++ks)
            af[m][ks] = *reinterpret_cast<const bf16x8*>(xrow + ks * 32);
    }
    float xh4min[8];                      // 0.5*min(xx) over each 4-row group
#pragma unroll
    for (int m = 0; m < 8; ++m) {
        float4 v = *reinterpret_cast<const float4*>(&xx[row0 + m * 16 + (lane >> 4) * 4]);
        xh4min[m] = 0.5f * fminf(fminf(v.x, v.y), fminf(v.z, v.w));
    }
    float hcv[NIT];                       // per-iter per-lane threshold
#pragma unroll
    for (int it = 0; it < NIT; ++it)
        hcv[it] = hc[cbase + it * BN + rB];

    // ---- stage tiles 0 and 1 (linear LDS dest, swizzled global source) ----
#define STAGE(IT, BUF)                                                         \
    {                                                                          \
        _Pragma("unroll")                                                      \
        for (int p = 0; p < 4; ++p) {                                          \
            int G = t + p * 256;                                               \
            int r = G >> 4;                                                    \
            int gsrc = (G & 15) ^ (r & 7);                                     \
            __builtin_amdgcn_global_load_lds(                                  \
                (cg_void*)(cb + (size_t)(cbase + (IT) * BN + r) * FEAT + gsrc * 8), \
                (lds_void_t*)((char*)cs[BUF] + G * 16), 16, 0, 0);             \
        }                                                                      \
    }
    STAGE(0, 0)
    STAGE(1, 1)

#pragma unroll
    for (int it = 0; it < NIT; ++it) {
        // wait own loads of tile it (4 newest = tile it+1 may stay in flight)
        if (it + 1 < NIT) asm volatile("s_waitcnt vmcnt(4)" ::: "memory");
        else              asm volatile("s_waitcnt vmcnt(0)" ::: "memory");
        __builtin_amdgcn_s_barrier();     // all waves' tile-it loads landed
        __builtin_amdgcn_sched_barrier(0);
        if (it + 2 < NIT) STAGE(it + 2, (it + 2) % 3)  // buf (it-1)%3: readers done

        const u16* brow = cs[it % 3] + rB * FEAT;
        f32x4 acc[8];
#pragma unroll
        for (int m = 0; m < 8; ++m) acc[m] = f32x4{0.f, 0.f, 0.f, 0.f};
        __builtin_amdgcn_s_setprio(1);
#pragma unroll
        for (int ks = 0; ks < 4; ++ks) {
            int gk = (ks * 4 + (lane >> 4)) ^ swz;
            bf16x8 bf = *reinterpret_cast<const bf16x8*>(brow + gk * 8);
#pragma unroll
            for (int m = 0; m < 8; ++m)
                acc[m] = __builtin_amdgcn_mfma_f32_16x16x32_bf16(af[m][ks], bf, acc[m], 0, 0, 0);
        }
        __builtin_amdgcn_s_setprio(0);

        // epilogue: pure VALU coarse check; rare exact path in noinline fn
        const float hv = hcv[it];
#pragma unroll
        for (int m = 0; m < 8; ++m) {
            float vmax = fmaxf(fmaxf(acc[m][0], acc[m][1]), fmaxf(acc[m][2], acc[m][3]));
            if (__builtin_expect(vmax - xh4min[m] > hv, 0))
                rare_path(acc[m][0], acc[m][1], acc[m][2], acc[m][3],
                          cbase + it * BN + rB, row0 + m * 16 + (lane >> 4) * 4,
                          xx, cc, scale, node_id, W, out);
        }
    }
#undef STAGE
}

// ---------------- launch ------------------------------------------------------
extern "C" void kernel_launch(void* const* d_in, const int* in_sizes, int n_in,
                              void* d_out, int out_size, void* d_ws, size_t ws_size,
                              hipStream_t stream) {
    const float* x       = (const float*)d_in[0];
    const float* centres = (const float*)d_in[1];
    const float* ls      = (const float*)d_in[2];
    const int*   node_id = (const int*)d_in[3];
    const float* W       = (const float*)d_in[4];
    const float* bias    = (const float*)d_in[5];
    float* out = (float*)d_out;

    // ws: xb 1MB | cbb 4MB | cc 64KB | scale 64KB | hc 64KB | xx 16KB
    char* p = (char*)d_ws;
    u16*   xb    = (u16*)p;    p += (size_t)BATCH * FEAT * 2;
    u16*   cbb   = (u16*)p;    p += (size_t)C_TOTAL * FEAT * 2;
    float* cc    = (float*)p;  p += (size_t)C_TOTAL * 4;
    float* scale = (float*)p;  p += (size_t)C_TOTAL * 4;
    float* hc    = (float*)p;  p += (size_t)C_TOTAL * 4;
    float* xx    = (float*)p;  p += (size_t)BATCH * 4;

    hipLaunchKernelGGL(prologue_kernel, dim3(2048 + 256 + 64), dim3(256), 0, stream,
                       x, centres, ls, bias, xb, cbb, cc, scale, hc, xx, out);
    hipLaunchKernelGGL(rbf_kernel, dim3(BATCH / BM, CSPLIT), dim3(256), 0, stream,
                       xb, cbb, hc, cc, scale, node_id, xx, W, out);
}